// Round 7
// baseline (7492.992 us; speedup 1.0000x reference)
//
#include <hip/hip_runtime.h>
#include <cstdint>
#include <cstddef>

// ---------------------------------------------------------------------------
// VanillaRNNTrajectoryPredictor — persistent weight-stationary RNN on MI355X
// B=4096, E=H=512, L=2, T_enc=33, T_dec=60, O=2
// 128 blocks x 1024 threads (16 waves); each block owns 32 batch rows
// (2 M-tiles sharing every weight fragment). Hidden state in LDS (bf16,
// XOR-swizzled). Weights packed per launch into [kstep][ntile][lane][8]
// fragment order so each (kstep,ntile) fragment is a contiguous 1 KB block.
//
// Round-7 change (barrier-serialized depth-1 pipeline was the bound):
// weight staging is now WAVE-PRIVATE: each wave DMAs exactly the 2 KB/kstep
// it consumes (its 2 ntiles) into a private 2-slot LDS ring via
// global_load_lds, and waits with counted s_waitcnt vmcnt(2) — NO per-kstep
// barrier. The 4 waves/SIMD drift and hide L2 latency via TLP. Block-wide
// __syncthreads only at hidden-state writeback boundaries (9/step).
// LDS = 3*32KB (H0,H1,INP; XA aliases INP) + 16 waves*2*2KB ring = 160 KB.
// ---------------------------------------------------------------------------

typedef __bf16 bf16x8 __attribute__((ext_vector_type(8)));
typedef float  f32x4  __attribute__((ext_vector_type(4)));

#define SZ    262144   // 512*512 elements per packed weight matrix
#define XDIM  198      // 6 + 32*6 input feature columns
#define NF    2        // MFMA n-fragments per wave (16 waves x 2 x 16 = 512 cols)
#define MB    32       // batch rows per block (2 M-tiles)
#define NBLK  128      // 4096 / MB
#define SLICE 16384    // ushorts per kstep slice: 32 ntiles * 64 lanes * 8

#define MFMA16(a, b, c) __builtin_amdgcn_mfma_f32_16x16x32_bf16((a), (b), (c), 0, 0, 0)

__device__ __host__ __forceinline__ unsigned short f2bf(float x) {
  uint32_t u = __builtin_bit_cast(uint32_t, x);
  u = (u + 0x7FFFu + ((u >> 16) & 1u)) >> 16;   // round-to-nearest-even
  return (unsigned short)u;
}

// Pack a row-major [N][Ksrc] f32 matrix into bf16 MFMA-fragment order, slice-
// contiguous: dst[((kstep*NT + ntile)*64 + lane)*8 + i] =
//   W[ntile*16 + (lane&15)][kstep*32 + ((lane>>4)&3)*8 + i],  NT = Npad/16.
__global__ void pack_w(const float* __restrict__ src, unsigned short* __restrict__ dst,
                       int N, int Ksrc, int Kpad) {
  int idx  = blockIdx.x * 256 + threadIdx.x;
  int Npad = (N + 15) & ~15;
  int total = Npad * Kpad;
  if (idx >= total) return;
  int n = idx / Kpad, k = idx - n * Kpad;
  float v = (n < N && k < Ksrc) ? src[n * Ksrc + k] : 0.f;
  int ntile = n >> 4, kstep = k >> 5, i = k & 7;
  int lane  = (((k >> 3) & 3) << 4) | (n & 15);
  int NT    = Npad >> 4;
  dst[((((kstep * NT) + ntile) * 64 + lane) << 3) + i] = f2bf(v);
}

// LDS fragment read from swizzled [MB][512] bf16 buffer.
// element (row,k) at ushort index row*512 + (k ^ ((row&7)<<3)).
__device__ __forceinline__ bf16x8 lds_frag(const unsigned short* buf, int m, int k) {
  int idx = m * 512 + (k ^ ((m & 7) << 3));
  return *reinterpret_cast<const bf16x8*>(buf + idx);
}

// Wave-private staging: this wave's 2 KB (ntiles 2wv, 2wv+1) of one kstep
// chunk -> private ring slot. LDS dest is wave-uniform; HW adds lane*16.
__device__ __forceinline__ void stage_chunk(const unsigned short* __restrict__ g,
                                            unsigned short* slot, int wv, int lane) {
  const unsigned short* g0 = g + wv * 1024 + lane * 8;
  __builtin_amdgcn_global_load_lds((const __attribute__((address_space(1))) void*)g0,
                                   (__attribute__((address_space(3))) void*)slot, 16, 0, 0);
  __builtin_amdgcn_global_load_lds((const __attribute__((address_space(1))) void*)(g0 + 512),
                                   (__attribute__((address_space(3))) void*)(slot + 512), 16, 0, 0);
}

// One barrier-free LDS-staged GEMM over K=512 (16 chunks): acc += A * W^T
// (this wave's 32-col slice, both M-tiles). Contract: Wg chunk 0 is already
// in flight (oldest outstanding); issues Wg[1..15] then Wnextg[0]; computes
// Wg[0..15]. sp = ring slot of the oldest in-flight chunk, rolls across calls.
__device__ __forceinline__ void gemm16(f32x4 acc[2][NF], const unsigned short* Abuf,
    const unsigned short* __restrict__ Wg, const unsigned short* __restrict__ Wnextg,
    unsigned short* ring, int& sp, int lane, int wv) {
  const int m    = lane & 15;
  const int ksub = (lane >> 4) << 3;
  for (int ks = 0; ks < 16; ++ks) {
    // A-reads first: independent of the wait, overlap with it
    bf16x8 a0 = lds_frag(Abuf, m, ks * 32 + ksub);
    bf16x8 a1 = lds_frag(Abuf + 16 * 512, m, ks * 32 + ksub);
    stage_chunk(ks < 15 ? (Wg + (ks + 1) * SLICE) : Wnextg,
                ring + (sp ^ 1) * 1024, wv, lane);
    asm volatile("s_waitcnt vmcnt(2)" ::: "memory");   // oldest chunk landed
    __builtin_amdgcn_sched_barrier(0);
    const unsigned short* cur = ring + sp * 1024;
    bf16x8 w0 = *reinterpret_cast<const bf16x8*>(cur + lane * 8);
    bf16x8 w1 = *reinterpret_cast<const bf16x8*>(cur + 512 + lane * 8);
    acc[0][0] = MFMA16(a0, w0, acc[0][0]);
    acc[1][0] = MFMA16(a1, w0, acc[1][0]);
    acc[0][1] = MFMA16(a0, w1, acc[0][1]);
    acc[1][1] = MFMA16(a1, w1, acc[1][1]);
    sp ^= 1;
  }
}

__device__ __forceinline__ void init_acc(f32x4 acc[2][NF], const float* __restrict__ b0,
                                         const float* __restrict__ b1, int lane, int wv) {
#pragma unroll
  for (int nf = 0; nf < NF; ++nf) {
    int col = (wv * NF + nf) * 16 + (lane & 15);
    float s = b0[col] + (b1 ? b1[col] : 0.f);
    acc[0][nf] = (f32x4){s, s, s, s};
    acc[1][nf] = (f32x4){s, s, s, s};
  }
}

// C/D layout: col = lane&15, row(within mtile) = (lane>>4)*4 + reg.
template <int ACT>  // 0 = tanh, 1 = relu
__device__ __forceinline__ void writeback(unsigned short* dst, const f32x4 acc[2][NF],
                                          int lane, int wv) {
#pragma unroll
  for (int mt = 0; mt < 2; ++mt) {
#pragma unroll
    for (int nf = 0; nf < NF; ++nf) {
#pragma unroll
      for (int j = 0; j < 4; ++j) {
        float v = acc[mt][nf][j];
        v = (ACT == 0) ? tanhf(v) : fmaxf(v, 0.f);
        int row = mt * 16 + ((lane >> 4) << 2) + j;
        int col = (wv * NF + nf) * 16 + (lane & 15);
        dst[row * 512 + (col ^ ((row & 7) << 3))] = f2bf(v);
      }
    }
  }
}

__global__ __launch_bounds__(1024, 4) void rnn_main(
    const float* __restrict__ x,
    const unsigned short* __restrict__ wp,
    const float* __restrict__ enc_bih, const float* __restrict__ enc_bhh,
    const float* __restrict__ dec_bih, const float* __restrict__ dec_bhh,
    const float* __restrict__ head_b1, const float* __restrict__ head_b2,
    const float* __restrict__ emb_main_b, const float* __restrict__ emb_veh_b,
    float* __restrict__ out) {
  __shared__ alignas(16) unsigned short H0[MB * 512];
  __shared__ alignas(16) unsigned short H1[MB * 512];
  __shared__ alignas(16) unsigned short INP[MB * 512];
  __shared__ alignas(16) unsigned short WRING[16][2][1024];   // total LDS = 160 KB

  unsigned short* XA = INP;   // alias: XA dead once emb writeback lands

  const int tid  = threadIdx.x;
  const int lane = tid & 63;
  const int wv   = tid >> 6;
  const int row0 = blockIdx.x * MB;
  unsigned short* ring = &WRING[wv][0][0];

  const unsigned short* encWih0 = wp + 0 * SZ;
  const unsigned short* encWih1 = wp + 1 * SZ;
  const unsigned short* encWhh0 = wp + 2 * SZ;
  const unsigned short* encWhh1 = wp + 3 * SZ;
  const unsigned short* decWih0 = wp + 4 * SZ;
  const unsigned short* decWih1 = wp + 5 * SZ;
  const unsigned short* decWhh0 = wp + 6 * SZ;
  const unsigned short* decWhh1 = wp + 7 * SZ;
  const unsigned short* headW1p = wp + 8 * SZ;
  const unsigned short* headW2p = wp + 9 * SZ;
  const unsigned short* vehp    = wp + 9 * SZ + 8192;
  const unsigned short* mainp   = wp + 9 * SZ + 8192 + 16384;

  for (int i = tid; i < MB * 512; i += 1024) { H0[i] = 0; H1[i] = 0; }
  __syncthreads();

  f32x4 acc[2][NF];
  int sp = 0;
  stage_chunk(vehp, ring, wv, lane);   // prologue: emb(t=0) chunk in flight

  // ---------------- encoder: 33 steps (t<32: vehicle tokens, t==32: main) ----
  for (int t = 0; t < 33; ++t) {
    // XA fill (aliases INP; INP's last readers finished 2 GEMMs ago)
    for (int i = tid; i < MB * 48; i += 1024) XA[i] = 0;
    __syncthreads();
    if (tid < MB * 6) {
      int m = tid / 6, kk = tid - m * 6;
      int cx = (t < 32) ? (6 + t * 6 + kk) : kk;
      XA[m * 48 + kk] = f2bf(x[(size_t)(row0 + m) * XDIM + cx]);
    }
    __syncthreads();
    // embedding GEMM: 1 chunk; chain -> encWih0 chunk 0
    {
      const float* be = (t < 32) ? emb_veh_b : emb_main_b;
      init_acc(acc, be, nullptr, lane, wv);
      int m = lane & 15, ksub = (lane >> 4) << 3;
      bf16x8 a0 = *reinterpret_cast<const bf16x8*>(XA + m * 48 + ksub);
      bf16x8 a1 = *reinterpret_cast<const bf16x8*>(XA + (16 + m) * 48 + ksub);
      stage_chunk(encWih0, ring + (sp ^ 1) * 1024, wv, lane);
      asm volatile("s_waitcnt vmcnt(2)" ::: "memory");
      __builtin_amdgcn_sched_barrier(0);
      const unsigned short* cur = ring + sp * 1024;
      bf16x8 w0 = *reinterpret_cast<const bf16x8*>(cur + lane * 8);
      bf16x8 w1 = *reinterpret_cast<const bf16x8*>(cur + 512 + lane * 8);
      acc[0][0] = MFMA16(a0, w0, acc[0][0]);
      acc[1][0] = MFMA16(a1, w0, acc[1][0]);
      acc[0][1] = MFMA16(a0, w1, acc[0][1]);
      acc[1][1] = MFMA16(a1, w1, acc[1][1]);
      sp ^= 1;
      __syncthreads();
      writeback<0>(INP, acc, lane, wv);   // overwrites XA alias; XA now dead
      __syncthreads();
    }
    // layer 0: H0 = tanh(INP@Wih0^T + bih0 + H0@Whh0^T + bhh0)
    init_acc(acc, enc_bih, enc_bhh, lane, wv);
    gemm16(acc, INP, encWih0, encWhh0, ring, sp, lane, wv);
    gemm16(acc, H0,  encWhh0, encWih1, ring, sp, lane, wv);
    __syncthreads();
    writeback<0>(H0, acc, lane, wv);
    __syncthreads();
    // layer 1: H1 = tanh(H0@Wih1^T + ... + H1@Whh1^T + ...)
    const unsigned short* after =
        (t < 31) ? vehp : (t == 31 ? mainp : decWih0);
    init_acc(acc, enc_bih + 512, enc_bhh + 512, lane, wv);
    gemm16(acc, H0, encWih1, encWhh1, ring, sp, lane, wv);
    gemm16(acc, H1, encWhh1, after,   ring, sp, lane, wv);
    __syncthreads();
    writeback<0>(H1, acc, lane, wv);
    __syncthreads();
  }

  // ---------------- decoder: 60 steps; input = previous top (H1) ------------
  for (int t = 0; t < 60; ++t) {
    // layer 0
    init_acc(acc, dec_bih, dec_bhh, lane, wv);
    gemm16(acc, H1, decWih0, decWhh0, ring, sp, lane, wv);
    gemm16(acc, H0, decWhh0, decWih1, ring, sp, lane, wv);
    __syncthreads();
    writeback<0>(H0, acc, lane, wv);
    __syncthreads();
    // layer 1
    init_acc(acc, dec_bih + 512, dec_bhh + 512, lane, wv);
    gemm16(acc, H0, decWih1, decWhh1, ring, sp, lane, wv);
    gemm16(acc, H1, decWhh1, headW1p, ring, sp, lane, wv);
    __syncthreads();
    writeback<0>(H1, acc, lane, wv);
    __syncthreads();
    // head layer 1: relu(H1@W1^T + b1) -> INP ; chain -> next step's decWih0
    init_acc(acc, head_b1, nullptr, lane, wv);
    gemm16(acc, H1, headW1p, decWih0, ring, sp, lane, wv);
    __syncthreads();
    writeback<1>(INP, acc, lane, wv);
    __syncthreads();   // head2 (waves 0,1) reads INP written by all waves

    // head layer 2 (N=2 padded to 16): waves 0,1 handle mtiles 0,1; W2 is a
    // 16 KB L2-hot stream read directly from global.
    if (wv < 2) {
      const unsigned short* A2 = INP + wv * 16 * 512;
      int m = lane & 15, ksub = (lane >> 4) << 3;
      f32x4 a2[4];
#pragma unroll
      for (int c = 0; c < 4; ++c) a2[c] = (f32x4){0.f, 0.f, 0.f, 0.f};
#pragma unroll
      for (int ks = 0; ks < 16; ++ks) {
        bf16x8 a = lds_frag(A2, m, ks * 32 + ksub);
        const bf16x8* bp =
            reinterpret_cast<const bf16x8*>(headW2p + (ks * 64 + lane) * 8);
        a2[ks & 3] = MFMA16(a, *bp, a2[ks & 3]);
      }
      f32x4 s = a2[0] + a2[1] + a2[2] + a2[3];
      if (m < 2) {
        float b2v = head_b2[m];
#pragma unroll
        for (int j = 0; j < 4; ++j) {
          int r = row0 + wv * 16 + ((lane >> 4) << 2) + j;
          out[(size_t)r * 120 + t * 2 + m] = tanhf(s[j] + b2v);
        }
      }
    }
    // waves >=2 proceed; they rendezvous with waves 0,1 at the next
    // writeback barrier, and nothing before that touches INP. The weight
    // ring slots are wave-private, so drift is safe.
  }
  // drain outstanding LDS-DMA before workgroup teardown
  asm volatile("s_waitcnt vmcnt(0)" ::: "memory");
}

extern "C" void kernel_launch(void* const* d_in, const int* in_sizes, int n_in,
                              void* d_out, int out_size, void* d_ws, size_t ws_size,
                              hipStream_t stream) {
  const float* x          = (const float*)d_in[0];
  const float* emb_main_W = (const float*)d_in[1];
  const float* emb_main_b = (const float*)d_in[2];
  const float* emb_veh_W  = (const float*)d_in[3];
  const float* emb_veh_b  = (const float*)d_in[4];
  const float* enc_Wih    = (const float*)d_in[5];
  const float* enc_Whh    = (const float*)d_in[6];
  const float* enc_bih    = (const float*)d_in[7];
  const float* enc_bhh    = (const float*)d_in[8];
  const float* dec_Wih    = (const float*)d_in[9];
  const float* dec_Whh    = (const float*)d_in[10];
  const float* dec_bih    = (const float*)d_in[11];
  const float* dec_bhh    = (const float*)d_in[12];
  const float* head_W1    = (const float*)d_in[13];
  const float* head_b1    = (const float*)d_in[14];
  const float* head_W2    = (const float*)d_in[15];
  const float* head_b2    = (const float*)d_in[16];

  unsigned short* wp = (unsigned short*)d_ws;   // 9*SZ + 8192 + 2*16384 ushorts ~ 4.8 MB

  dim3 blk(256);
  auto P = [&](const float* src, unsigned short* dst) {
    hipLaunchKernelGGL(pack_w, dim3(1024), blk, 0, stream, src, dst, 512, 512, 512);
  };
  P(enc_Wih + 0 * SZ, wp + 0 * SZ);
  P(enc_Wih + 1 * SZ, wp + 1 * SZ);
  P(enc_Whh + 0 * SZ, wp + 2 * SZ);
  P(enc_Whh + 1 * SZ, wp + 3 * SZ);
  P(dec_Wih + 0 * SZ, wp + 4 * SZ);
  P(dec_Wih + 1 * SZ, wp + 5 * SZ);
  P(dec_Whh + 0 * SZ, wp + 6 * SZ);
  P(dec_Whh + 1 * SZ, wp + 7 * SZ);
  P(head_W1, wp + 8 * SZ);
  hipLaunchKernelGGL(pack_w, dim3(32), blk, 0, stream, head_W2, wp + 9 * SZ, 2, 512, 512);
  hipLaunchKernelGGL(pack_w, dim3(64), blk, 0, stream, emb_veh_W, wp + 9 * SZ + 8192, 512, 6, 32);
  hipLaunchKernelGGL(pack_w, dim3(64), blk, 0, stream, emb_main_W, wp + 9 * SZ + 8192 + 16384, 512, 6, 32);

  hipLaunchKernelGGL(rnn_main, dim3(NBLK), dim3(1024), 0, stream,
                     x, (const unsigned short*)wp, enc_bih, enc_bhh, dec_bih, dec_bhh,
                     head_b1, head_b2, emb_main_b, emb_veh_b, (float*)d_out);
}

// Round 8
// 2533.658 us; speedup vs baseline: 2.9574x; 2.9574x over previous
//
#include <hip/hip_runtime.h>
#include <cstdint>
#include <cstddef>

// ---------------------------------------------------------------------------
// VanillaRNNTrajectoryPredictor — persistent weight-stationary RNN on MI355X
// B=4096, E=H=512, L=2, T_enc=33, T_dec=60, O=2
// 128 blocks x 1024 threads (16 waves); each block owns 32 batch rows
// (2 M-tiles sharing every weight fragment). Hidden state in LDS (bf16,
// XOR-swizzled). Weights packed per launch into [kstep][ntile][lane][8]
// fragment order so each K=32 slice is a contiguous 32 KB block.
//
// Round-8: round-6 block-lockstep slice pipeline (proven L2-resident,
// FETCH ~32 MB) but with DRAIN-FREE barriers:
//  - wave wv stages exactly the 2 KB region of each slice that it reads
//    -> a counted s_waitcnt vmcnt(2) covers its own data (no vmcnt(0))
//  - raw s_barrier per kstep (lockstep throttle for L2 coherence only)
//  - lgkmcnt(0)+s_barrier at LDS writeback handoffs (vmem stays in flight)
//  - A-fragments prefetched into registers; biases preloaded to registers
// LDS = 3*32KB (H0,H1,INP; XA aliases INP) + 2x32KB slice ring = 160 KB.
// ---------------------------------------------------------------------------

typedef __bf16 bf16x8 __attribute__((ext_vector_type(8)));
typedef float  f32x4  __attribute__((ext_vector_type(4)));

#define SZ    262144   // 512*512 elements per packed weight matrix
#define XDIM  198      // 6 + 32*6 input feature columns
#define NF    2        // MFMA n-fragments per wave (16 waves x 2 x 16 = 512 cols)
#define MB    32       // batch rows per block (2 M-tiles)
#define NBLK  128      // 4096 / MB
#define SLICE 16384    // ushorts per kstep slice: 32 ntiles * 64 lanes * 8

#define MFMA16(a, b, c) __builtin_amdgcn_mfma_f32_16x16x32_bf16((a), (b), (c), 0, 0, 0)
#define AS1 __attribute__((address_space(1)))
#define AS3 __attribute__((address_space(3)))

__device__ __host__ __forceinline__ unsigned short f2bf(float x) {
  uint32_t u = __builtin_bit_cast(uint32_t, x);
  u = (u + 0x7FFFu + ((u >> 16) & 1u)) >> 16;   // round-to-nearest-even
  return (unsigned short)u;
}

// Pack a row-major [N][Ksrc] f32 matrix into bf16 MFMA-fragment order, slice-
// contiguous: dst[((kstep*NT + ntile)*64 + lane)*8 + i] =
//   W[ntile*16 + (lane&15)][kstep*32 + ((lane>>4)&3)*8 + i],  NT = Npad/16.
__global__ void pack_w(const float* __restrict__ src, unsigned short* __restrict__ dst,
                       int N, int Ksrc, int Kpad) {
  int idx  = blockIdx.x * 256 + threadIdx.x;
  int Npad = (N + 15) & ~15;
  int total = Npad * Kpad;
  if (idx >= total) return;
  int n = idx / Kpad, k = idx - n * Kpad;
  float v = (n < N && k < Ksrc) ? src[n * Ksrc + k] : 0.f;
  int ntile = n >> 4, kstep = k >> 5, i = k & 7;
  int lane  = (((k >> 3) & 3) << 4) | (n & 15);
  int NT    = Npad >> 4;
  dst[((((kstep * NT) + ntile) * 64 + lane) << 3) + i] = f2bf(v);
}

// LDS fragment read from swizzled [MB][512] bf16 buffer.
// element (row,k) at ushort index row*512 + (k ^ ((row&7)<<3)).
__device__ __forceinline__ bf16x8 lds_frag(const unsigned short* buf, int m, int k) {
  int idx = m * 512 + (k ^ ((m & 7) << 3));
  return *reinterpret_cast<const bf16x8*>(buf + idx);
}

// LDS producer->consumer handoff: drain DS ops, barrier. vmcnt NOT drained —
// the chained weight-slice DMA stays in flight across this barrier.
__device__ __forceinline__ void bar_sync_lds() {
  asm volatile("s_waitcnt lgkmcnt(0)" ::: "memory");
  __builtin_amdgcn_s_barrier();
  __builtin_amdgcn_sched_barrier(0);
}
// Pure lockstep throttle (keeps the block's slice walk L2-coherent).
__device__ __forceinline__ void bar_throttle() {
  __builtin_amdgcn_s_barrier();
  __builtin_amdgcn_sched_barrier(0);
}

// Stage this wave's 2 KB region of one 32 KB slice (2 x 1 KB DMA).
// gslice/ldst: slice bases; wave region = +wv*1024 ushorts. LDS dest is
// wave-uniform; HW adds lane*16 B, mirroring the per-lane global src.
__device__ __forceinline__ void stage_own(const unsigned short* __restrict__ gslice,
                                          unsigned short* lslice, int wv, int lane) {
  const unsigned short* g0 = gslice + wv * 1024 + lane * 8;
  unsigned short* l0 = lslice + wv * 1024;
  __builtin_amdgcn_global_load_lds((const AS1 void*)g0, (AS3 void*)l0, 16, 0, 0);
  __builtin_amdgcn_global_load_lds((const AS1 void*)(g0 + 512), (AS3 void*)(l0 + 512), 16, 0, 0);
}

// One lockstep LDS-staged GEMM over K=512 (16 slices): acc += A * W^T
// (this wave's 32-col slice, both M-tiles). Contract: Wg slice 0 already in
// flight into buf[sp] (oldest outstanding). Issues Wg[1..15] then Wnextg[0].
__device__ __forceinline__ void gemm16(f32x4 acc[2][NF], const unsigned short* Abuf,
    const unsigned short* __restrict__ Wg, const unsigned short* __restrict__ Wnextg,
    unsigned short* wb0, unsigned short* wb1, int& sp, int lane, int wv) {
  const int m    = lane & 15;
  const int ksub = (lane >> 4) << 3;
  const int wreg = wv * 1024;
  bf16x8 a0 = lds_frag(Abuf, m, ksub);
  bf16x8 a1 = lds_frag(Abuf + 16 * 512, m, ksub);
  for (int ks = 0; ks < 16; ++ks) {
    bar_throttle();                       // raw barrier: lockstep, no drain
    stage_own((ks < 15 ? (Wg + (ks + 1) * SLICE) : Wnextg),
              (sp ? wb0 : wb1), wv, lane);
    asm volatile("s_waitcnt vmcnt(2)" ::: "memory");   // own slice-ks landed
    __builtin_amdgcn_sched_barrier(0);
    const unsigned short* cur = (sp ? wb1 : wb0) + wreg;
    bf16x8 w0 = *reinterpret_cast<const bf16x8*>(cur + lane * 8);
    bf16x8 w1 = *reinterpret_cast<const bf16x8*>(cur + 512 + lane * 8);
    bf16x8 a0n = a0, a1n = a1;
    if (ks < 15) {                        // A-prefetch overlaps MFMA phase
      a0n = lds_frag(Abuf, m, (ks + 1) * 32 + ksub);
      a1n = lds_frag(Abuf + 16 * 512, m, (ks + 1) * 32 + ksub);
    }
    acc[0][0] = MFMA16(a0, w0, acc[0][0]);
    acc[1][0] = MFMA16(a1, w0, acc[1][0]);
    acc[0][1] = MFMA16(a0, w1, acc[0][1]);
    acc[1][1] = MFMA16(a1, w1, acc[1][1]);
    a0 = a0n; a1 = a1n;
    sp ^= 1;
  }
}

__device__ __forceinline__ void init_acc2(f32x4 acc[2][NF], float b0, float b1) {
  acc[0][0] = (f32x4){b0, b0, b0, b0};
  acc[1][0] = (f32x4){b0, b0, b0, b0};
  acc[0][1] = (f32x4){b1, b1, b1, b1};
  acc[1][1] = (f32x4){b1, b1, b1, b1};
}

// C/D layout: col = lane&15, row(within mtile) = (lane>>4)*4 + reg.
template <int ACT>  // 0 = tanh, 1 = relu
__device__ __forceinline__ void writeback(unsigned short* dst, const f32x4 acc[2][NF],
                                          int lane, int wv) {
#pragma unroll
  for (int mt = 0; mt < 2; ++mt) {
#pragma unroll
    for (int nf = 0; nf < NF; ++nf) {
#pragma unroll
      for (int j = 0; j < 4; ++j) {
        float v = acc[mt][nf][j];
        v = (ACT == 0) ? tanhf(v) : fmaxf(v, 0.f);
        int row = mt * 16 + ((lane >> 4) << 2) + j;
        int col = (wv * NF + nf) * 16 + (lane & 15);
        dst[row * 512 + (col ^ ((row & 7) << 3))] = f2bf(v);
      }
    }
  }
}

__global__ __launch_bounds__(1024, 4) void rnn_main(
    const float* __restrict__ x,
    const unsigned short* __restrict__ wp,
    const float* __restrict__ enc_bih, const float* __restrict__ enc_bhh,
    const float* __restrict__ dec_bih, const float* __restrict__ dec_bhh,
    const float* __restrict__ head_b1, const float* __restrict__ head_b2,
    const float* __restrict__ emb_main_b, const float* __restrict__ emb_veh_b,
    float* __restrict__ out) {
  __shared__ alignas(16) unsigned short H0[MB * 512];
  __shared__ alignas(16) unsigned short H1[MB * 512];
  __shared__ alignas(16) unsigned short INP[MB * 512];
  __shared__ alignas(16) unsigned short WBUF[2][SLICE];   // total LDS = 160 KB

  unsigned short* XA = INP;   // alias: XA dead once emb writeback lands

  const int tid  = threadIdx.x;
  const int lane = tid & 63;
  const int wv   = tid >> 6;
  const int row0 = blockIdx.x * MB;
  const int wreg = wv * 1024;

  const unsigned short* encWih0 = wp + 0 * SZ;
  const unsigned short* encWih1 = wp + 1 * SZ;
  const unsigned short* encWhh0 = wp + 2 * SZ;
  const unsigned short* encWhh1 = wp + 3 * SZ;
  const unsigned short* decWih0 = wp + 4 * SZ;
  const unsigned short* decWih1 = wp + 5 * SZ;
  const unsigned short* decWhh0 = wp + 6 * SZ;
  const unsigned short* decWhh1 = wp + 7 * SZ;
  const unsigned short* headW1p = wp + 8 * SZ;
  const unsigned short* headW2p = wp + 9 * SZ;
  const unsigned short* vehp    = wp + 9 * SZ + 8192;
  const unsigned short* mainp   = wp + 9 * SZ + 8192 + 16384;

  // bias preload -> registers (keeps the steady-state vmcnt queue clean)
  const int c0 = (wv * NF + 0) * 16 + (lane & 15);
  const int c1 = c0 + 16;
  const float bEv0 = emb_veh_b[c0],  bEv1 = emb_veh_b[c1];
  const float bEm0 = emb_main_b[c0], bEm1 = emb_main_b[c1];
  const float bE00 = enc_bih[c0] + enc_bhh[c0];
  const float bE01 = enc_bih[c1] + enc_bhh[c1];
  const float bE10 = enc_bih[512 + c0] + enc_bhh[512 + c0];
  const float bE11 = enc_bih[512 + c1] + enc_bhh[512 + c1];
  const float bD00 = dec_bih[c0] + dec_bhh[c0];
  const float bD01 = dec_bih[c1] + dec_bhh[c1];
  const float bD10 = dec_bih[512 + c0] + dec_bhh[512 + c0];
  const float bD11 = dec_bih[512 + c1] + dec_bhh[512 + c1];
  const float bH0 = head_b1[c0], bH1 = head_b1[c1];
  const float b2v = head_b2[lane & 1];

  for (int i = tid; i < MB * 512; i += 1024) { H0[i] = 0; H1[i] = 0; }
  bar_sync_lds();

  f32x4 acc[2][NF];
  int sp = 0;
  stage_own(vehp, WBUF[0], wv, lane);   // prologue: emb(t=0) slice in flight

  // ---------------- encoder: 33 steps (t<32: vehicle tokens, t==32: main) ----
  for (int t = 0; t < 33; ++t) {
    // XA fill (aliases INP; INP's last readers finished 2 GEMMs ago)
    for (int i = tid; i < MB * 48; i += 1024) XA[i] = 0;
    bar_sync_lds();
    if (tid < MB * 6) {
      int m = tid / 6, kk = tid - m * 6;
      int cx = (t < 32) ? (6 + t * 6 + kk) : kk;
      XA[m * 48 + kk] = f2bf(x[(size_t)(row0 + m) * XDIM + cx]);
    }
    bar_sync_lds();
    // embedding GEMM: 1 slice; chain -> encWih0 slice 0
    {
      init_acc2(acc, (t < 32) ? bEv0 : bEm0, (t < 32) ? bEv1 : bEm1);
      int m = lane & 15, ksub = (lane >> 4) << 3;
      bf16x8 a0 = *reinterpret_cast<const bf16x8*>(XA + m * 48 + ksub);
      bf16x8 a1 = *reinterpret_cast<const bf16x8*>(XA + (16 + m) * 48 + ksub);
      bar_throttle();
      stage_own(encWih0, WBUF[sp ^ 1], wv, lane);
      asm volatile("s_waitcnt vmcnt(2)" ::: "memory");
      __builtin_amdgcn_sched_barrier(0);
      const unsigned short* cur = WBUF[sp] + wreg;
      bf16x8 w0 = *reinterpret_cast<const bf16x8*>(cur + lane * 8);
      bf16x8 w1 = *reinterpret_cast<const bf16x8*>(cur + 512 + lane * 8);
      acc[0][0] = MFMA16(a0, w0, acc[0][0]);
      acc[1][0] = MFMA16(a1, w0, acc[1][0]);
      acc[0][1] = MFMA16(a0, w1, acc[0][1]);
      acc[1][1] = MFMA16(a1, w1, acc[1][1]);
      sp ^= 1;
      bar_sync_lds();
      writeback<0>(INP, acc, lane, wv);   // overwrites XA alias; XA now dead
      bar_sync_lds();
    }
    // layer 0: H0 = tanh(INP@Wih0^T + bih0 + H0@Whh0^T + bhh0)
    init_acc2(acc, bE00, bE01);
    gemm16(acc, INP, encWih0, encWhh0, WBUF[0], WBUF[1], sp, lane, wv);
    gemm16(acc, H0,  encWhh0, encWih1, WBUF[0], WBUF[1], sp, lane, wv);
    bar_sync_lds();
    writeback<0>(H0, acc, lane, wv);
    bar_sync_lds();
    // layer 1: H1 = tanh(H0@Wih1^T + ... + H1@Whh1^T + ...)
    const unsigned short* after =
        (t < 31) ? vehp : (t == 31 ? mainp : decWih0);
    init_acc2(acc, bE10, bE11);
    gemm16(acc, H0, encWih1, encWhh1, WBUF[0], WBUF[1], sp, lane, wv);
    gemm16(acc, H1, encWhh1, after,   WBUF[0], WBUF[1], sp, lane, wv);
    bar_sync_lds();
    writeback<0>(H1, acc, lane, wv);
    bar_sync_lds();
  }

  // ---------------- decoder: 60 steps; input = previous top (H1) ------------
  for (int t = 0; t < 60; ++t) {
    // layer 0
    init_acc2(acc, bD00, bD01);
    gemm16(acc, H1, decWih0, decWhh0, WBUF[0], WBUF[1], sp, lane, wv);
    gemm16(acc, H0, decWhh0, decWih1, WBUF[0], WBUF[1], sp, lane, wv);
    bar_sync_lds();
    writeback<0>(H0, acc, lane, wv);
    bar_sync_lds();
    // layer 1
    init_acc2(acc, bD10, bD11);
    gemm16(acc, H0, decWih1, decWhh1, WBUF[0], WBUF[1], sp, lane, wv);
    gemm16(acc, H1, decWhh1, headW1p, WBUF[0], WBUF[1], sp, lane, wv);
    bar_sync_lds();
    writeback<0>(H1, acc, lane, wv);
    bar_sync_lds();
    // head layer 1: relu(H1@W1^T + b1) -> INP ; chain -> next step's decWih0
    init_acc2(acc, bH0, bH1);
    gemm16(acc, H1, headW1p, decWih0, WBUF[0], WBUF[1], sp, lane, wv);
    bar_sync_lds();
    writeback<1>(INP, acc, lane, wv);
    bar_sync_lds();   // head2 (waves 0,1) reads INP written by all waves

    // head layer 2 (N=2 padded to 16): waves 0,1 handle mtiles 0,1; W2 is a
    // 16 KB L2-hot stream read directly from global. No barriers inside.
    if (wv < 2) {
      const unsigned short* A2 = INP + wv * 16 * 512;
      int m = lane & 15, ksub = (lane >> 4) << 3;
      f32x4 a2[4];
#pragma unroll
      for (int c = 0; c < 4; ++c) a2[c] = (f32x4){0.f, 0.f, 0.f, 0.f};
#pragma unroll
      for (int ks = 0; ks < 16; ++ks) {
        bf16x8 a = lds_frag(A2, m, ks * 32 + ksub);
        const bf16x8* bp =
            reinterpret_cast<const bf16x8*>(headW2p + (ks * 64 + lane) * 8);
        a2[ks & 3] = MFMA16(a, *bp, a2[ks & 3]);
      }
      f32x4 s = a2[0] + a2[1] + a2[2] + a2[3];
      if (m < 2) {
#pragma unroll
        for (int j = 0; j < 4; ++j) {
          int r = row0 + wv * 16 + ((lane >> 4) << 2) + j;
          out[(size_t)r * 120 + t * 2 + m] = tanhf(s[j] + b2v);
        }
      }
    }
    // waves >=2 proceed to the next gemm16's kstep-0 barrier and wait there
    // for waves 0,1; nothing before that barrier touches INP or WBUF.
  }
  // drain outstanding LDS-DMA before workgroup teardown
  asm volatile("s_waitcnt vmcnt(0)" ::: "memory");
}

extern "C" void kernel_launch(void* const* d_in, const int* in_sizes, int n_in,
                              void* d_out, int out_size, void* d_ws, size_t ws_size,
                              hipStream_t stream) {
  const float* x          = (const float*)d_in[0];
  const float* emb_main_W = (const float*)d_in[1];
  const float* emb_main_b = (const float*)d_in[2];
  const float* emb_veh_W  = (const float*)d_in[3];
  const float* emb_veh_b  = (const float*)d_in[4];
  const float* enc_Wih    = (const float*)d_in[5];
  const float* enc_Whh    = (const float*)d_in[6];
  const float* enc_bih    = (const float*)d_in[7];
  const float* enc_bhh    = (const float*)d_in[8];
  const float* dec_Wih    = (const float*)d_in[9];
  const float* dec_Whh    = (const float*)d_in[10];
  const float* dec_bih    = (const float*)d_in[11];
  const float* dec_bhh    = (const float*)d_in[12];
  const float* head_W1    = (const float*)d_in[13];
  const float* head_b1    = (const float*)d_in[14];
  const float* head_W2    = (const float*)d_in[15];
  const float* head_b2    = (const float*)d_in[16];

  unsigned short* wp = (unsigned short*)d_ws;   // 9*SZ + 8192 + 2*16384 ushorts ~ 4.8 MB

  dim3 blk(256);
  auto P = [&](const float* src, unsigned short* dst) {
    hipLaunchKernelGGL(pack_w, dim3(1024), blk, 0, stream, src, dst, 512, 512, 512);
  };
  P(enc_Wih + 0 * SZ, wp + 0 * SZ);
  P(enc_Wih + 1 * SZ, wp + 1 * SZ);
  P(enc_Whh + 0 * SZ, wp + 2 * SZ);
  P(enc_Whh + 1 * SZ, wp + 3 * SZ);
  P(dec_Wih + 0 * SZ, wp + 4 * SZ);
  P(dec_Wih + 1 * SZ, wp + 5 * SZ);
  P(dec_Whh + 0 * SZ, wp + 6 * SZ);
  P(dec_Whh + 1 * SZ, wp + 7 * SZ);
  P(head_W1, wp + 8 * SZ);
  hipLaunchKernelGGL(pack_w, dim3(32), blk, 0, stream, head_W2, wp + 9 * SZ, 2, 512, 512);
  hipLaunchKernelGGL(pack_w, dim3(64), blk, 0, stream, emb_veh_W, wp + 9 * SZ + 8192, 512, 6, 32);
  hipLaunchKernelGGL(pack_w, dim3(64), blk, 0, stream, emb_main_W, wp + 9 * SZ + 8192 + 16384, 512, 6, 32);

  hipLaunchKernelGGL(rnn_main, dim3(NBLK), dim3(1024), 0, stream,
                     x, (const unsigned short*)wp, enc_bih, enc_bhh, dec_bih, dec_bhh,
                     head_b1, head_b2, emb_main_b, emb_veh_b, (float*)d_out);
}